// Round 1
// baseline (981.009 us; speedup 1.0000x reference)
//
#include <hip/hip_runtime.h>
#include <stdint.h>

#define D_MODEL 1024
#define NHEADS 16
#define HDIM 64
#define CHUNK 2048
#define SEQ 8192
#define NCHUNK 4

typedef __attribute__((ext_vector_type(8))) short bf16x8;
typedef __attribute__((ext_vector_type(4))) float f32x4;

union V16 { uint4 u; short s[8]; };

static __device__ __forceinline__ short f2bf(float f) {
    unsigned int u = __builtin_bit_cast(unsigned int, f);
    u = (u + 0x7FFFu + ((u >> 16) & 1u)) >> 16;
    return (short)u;
}

static __device__ __forceinline__ void gl_lds16(const void* g, void* l) {
    __builtin_amdgcn_global_load_lds((__attribute__((address_space(1))) void*)g,
                                     (__attribute__((address_space(3))) void*)l,
                                     16, 0, 0);
}

// ---------------- fp32 -> bf16 conversion ----------------
__global__ void cvt_f32_bf16(const float* __restrict__ in, short* __restrict__ out, int n) {
    int i = (blockIdx.x * 256 + threadIdx.x) * 4;
    if (i >= n) return;
    float4 v = *(const float4*)(in + i);
    short4 o;
    o.x = f2bf(v.x); o.y = f2bf(v.y); o.z = f2bf(v.z); o.w = f2bf(v.w);
    *(short4*)(out + i) = o;
}

// ---------------- bf16 GEMM: C[M,N] = A[M,K] * B[N,K]^T ----------------
// 128x128 block tile, 256 threads (4 waves, 2x2 of 64x64), BK=32.
template<bool OUT_BF16>
__global__ __launch_bounds__(256) void gemm_bt(const short* __restrict__ A,
                                               const short* __restrict__ B,
                                               void* __restrict__ Cout,
                                               int M, int N, int K) {
    __shared__ __align__(16) short As[128 * 32];
    __shared__ __align__(16) short Bs[128 * 32];
    const int tid  = threadIdx.x;
    const int lane = tid & 63;
    const int w    = tid >> 6;
    const int wr   = w >> 1, wc = w & 1;
    const int rowBase = blockIdx.y * 128;
    const int colBase = blockIdx.x * 128;
    const int quad = lane >> 4;
    const int cl   = lane & 15;

    f32x4 acc[4][4];
    #pragma unroll
    for (int i = 0; i < 4; ++i)
        #pragma unroll
        for (int j = 0; j < 4; ++j)
            acc[i][j] = (f32x4){0.f, 0.f, 0.f, 0.f};

    const int tr = tid >> 2;        // 0..63 (row within 64-row half)
    const int tc = (tid & 3) * 8;   // 0,8,16,24 (k element offset)
    const short* gA0 = A + (size_t)(rowBase + tr) * K + tc;
    const short* gA1 = A + (size_t)(rowBase + 64 + tr) * K + tc;
    const short* gB0 = B + (size_t)(colBase + tr) * K + tc;
    const short* gB1 = B + (size_t)(colBase + 64 + tr) * K + tc;

    for (int k0 = 0; k0 < K; k0 += 32) {
        gl_lds16(gA0 + k0, &As[tid * 8]);
        gl_lds16(gA1 + k0, &As[2048 + tid * 8]);
        gl_lds16(gB0 + k0, &Bs[tid * 8]);
        gl_lds16(gB1 + k0, &Bs[2048 + tid * 8]);
        __syncthreads();

        bf16x8 af[4], bfr[4];
        #pragma unroll
        for (int mi = 0; mi < 4; ++mi)
            af[mi] = *(const bf16x8*)&As[(wr * 64 + mi * 16 + cl) * 32 + quad * 8];
        #pragma unroll
        for (int ni = 0; ni < 4; ++ni)
            bfr[ni] = *(const bf16x8*)&Bs[(wc * 64 + ni * 16 + cl) * 32 + quad * 8];

        #pragma unroll
        for (int mi = 0; mi < 4; ++mi)
            #pragma unroll
            for (int ni = 0; ni < 4; ++ni)
                acc[mi][ni] = __builtin_amdgcn_mfma_f32_16x16x32_bf16(af[mi], bfr[ni], acc[mi][ni], 0, 0, 0);
        __syncthreads();
    }

    // Epilogue: D row = quad*4+reg, col = lane&15 (verified m89/m91 layout)
    #pragma unroll
    for (int mi = 0; mi < 4; ++mi)
        #pragma unroll
        for (int ni = 0; ni < 4; ++ni)
            #pragma unroll
            for (int r = 0; r < 4; ++r) {
                int row = rowBase + wr * 64 + mi * 16 + quad * 4 + r;
                int col = colBase + wc * 64 + ni * 16 + cl;
                if (OUT_BF16)
                    ((short*)Cout)[(size_t)row * N + col] = f2bf(acc[mi][ni][r]);
                else
                    ((float*)Cout)[(size_t)row * N + col] = acc[mi][ni][r];
            }
}

// ---------------- flash attention, chunk-local causal ----------------
// grid: (CHUNK/64, NCHUNK, NHEADS), block 256 = 4 independent waves.
// Each wave: 16 q rows; iterates 32-key tiles with online softmax.
__global__ __launch_bounds__(256) void attn_kernel(const short* __restrict__ Q,
                                                   const short* __restrict__ K,
                                                   const short* __restrict__ V,
                                                   short* __restrict__ O) {
    // per-wave LDS: K tile [32][64], V^T tile [64][32], P tile [16][32]
    __shared__ __align__(16) short smem[4 * (32 * 64 + 64 * 32 + 16 * 32)];
    const int tid  = threadIdx.x;
    const int lane = tid & 63;
    const int w    = tid >> 6;
    short* Kt = smem + w * (32 * 64 + 64 * 32 + 16 * 32);
    short* Vt = Kt + 32 * 64;
    short* Pt = Vt + 64 * 32;

    const int h = blockIdx.z;
    const int n = blockIdx.y;
    const int qbase = blockIdx.x * 64 + w * 16;  // within chunk
    const int quad = lane >> 4;
    const int cl   = lane & 15;
    const size_t chunkOff = (size_t)n * CHUNK * D_MODEL + h * HDIM;

    // Q fragments (A layout): lane holds Q[qbase+cl][quad*8+j] (+32 for hi half)
    const short* Qg = Q + chunkOff + (size_t)(qbase + cl) * D_MODEL;
    bf16x8 qa = *(const bf16x8*)(Qg + quad * 8);
    bf16x8 qb = *(const bf16x8*)(Qg + 32 + quad * 8);

    float m_run[4], l_run[4];
    f32x4 o_acc[4];
    #pragma unroll
    for (int r = 0; r < 4; ++r) { m_run[r] = -3.0e38f; l_run[r] = 0.f; }
    #pragma unroll
    for (int dt = 0; dt < 4; ++dt) o_acc[dt] = (f32x4){0.f, 0.f, 0.f, 0.f};

    const int ntiles = (qbase + 15) / 32 + 1;
    const float cs = 0.18033688011f;  // log2(e)/8   (1/sqrt(64) scale, base-2 domain)

    for (int t = 0; t < ntiles; ++t) {
        const int kb = t * 32;
        // drain previous iteration's LDS reads before overwriting tiles
        __asm__ volatile("s_waitcnt lgkmcnt(0)" ::: "memory");
        // stage K tile (copy) and V tile (transposed)
        #pragma unroll
        for (int i = 0; i < 4; ++i) {
            int f = i * 512 + lane * 8;
            int r = f >> 6, c = f & 63;
            V16 kv, vv;
            kv.u = *(const uint4*)(K + chunkOff + (size_t)(kb + r) * D_MODEL + c);
            *(uint4*)(Kt + f) = kv.u;
            vv.u = *(const uint4*)(V + chunkOff + (size_t)(kb + r) * D_MODEL + c);
            #pragma unroll
            for (int j = 0; j < 8; ++j) Vt[(c + j) * 32 + r] = vv.s[j];
        }
        __asm__ volatile("s_waitcnt lgkmcnt(0)" ::: "memory");

        // S = Q K^T : two 16-key column tiles, K-dim 64 = 2 MFMAs each
        f32x4 s0 = (f32x4){0.f, 0.f, 0.f, 0.f};
        f32x4 s1 = (f32x4){0.f, 0.f, 0.f, 0.f};
        bf16x8 k0a = *(const bf16x8*)(Kt + cl * 64 + quad * 8);
        bf16x8 k0b = *(const bf16x8*)(Kt + cl * 64 + 32 + quad * 8);
        bf16x8 k1a = *(const bf16x8*)(Kt + (16 + cl) * 64 + quad * 8);
        bf16x8 k1b = *(const bf16x8*)(Kt + (16 + cl) * 64 + 32 + quad * 8);
        s0 = __builtin_amdgcn_mfma_f32_16x16x32_bf16(qa, k0a, s0, 0, 0, 0);
        s0 = __builtin_amdgcn_mfma_f32_16x16x32_bf16(qb, k0b, s0, 0, 0, 0);
        s1 = __builtin_amdgcn_mfma_f32_16x16x32_bf16(qa, k1a, s1, 0, 0, 0);
        s1 = __builtin_amdgcn_mfma_f32_16x16x32_bf16(qb, k1b, s1, 0, 0, 0);

        const bool full = (kb + 31) <= qbase;  // wave-uniform
        #pragma unroll
        for (int r = 0; r < 4; ++r) {
            float v0 = s0[r] * cs, v1 = s1[r] * cs;
            if (!full) {
                int q = qbase + quad * 4 + r;
                if (kb + cl > q)      v0 = -3.0e38f;
                if (kb + 16 + cl > q) v1 = -3.0e38f;
            }
            float mx = fmaxf(v0, v1);
            mx = fmaxf(mx, __shfl_xor(mx, 1));
            mx = fmaxf(mx, __shfl_xor(mx, 2));
            mx = fmaxf(mx, __shfl_xor(mx, 4));
            mx = fmaxf(mx, __shfl_xor(mx, 8));
            float mnew  = fmaxf(m_run[r], mx);
            float alpha = __builtin_amdgcn_exp2f(m_run[r] - mnew);
            float p0 = __builtin_amdgcn_exp2f(v0 - mnew);
            float p1 = __builtin_amdgcn_exp2f(v1 - mnew);
            float rs = p0 + p1;
            rs += __shfl_xor(rs, 1);
            rs += __shfl_xor(rs, 2);
            rs += __shfl_xor(rs, 4);
            rs += __shfl_xor(rs, 8);
            l_run[r] = l_run[r] * alpha + rs;
            m_run[r] = mnew;
            o_acc[0][r] *= alpha; o_acc[1][r] *= alpha;
            o_acc[2][r] *= alpha; o_acc[3][r] *= alpha;
            // P in C layout -> LDS (row = quad*4+r, cols cl and 16+cl)
            Pt[(quad * 4 + r) * 32 + cl]      = f2bf(p0);
            Pt[(quad * 4 + r) * 32 + 16 + cl] = f2bf(p1);
        }
        __asm__ volatile("s_waitcnt lgkmcnt(0)" ::: "memory");

        // O += P V : A = P[16,32] (A layout), B = V[32,64] via Vt, 4 d-tiles
        bf16x8 pf = *(const bf16x8*)(Pt + cl * 32 + quad * 8);
        #pragma unroll
        for (int dt = 0; dt < 4; ++dt) {
            bf16x8 vf = *(const bf16x8*)(Vt + (dt * 16 + cl) * 32 + quad * 8);
            o_acc[dt] = __builtin_amdgcn_mfma_f32_16x16x32_bf16(pf, vf, o_acc[dt], 0, 0, 0);
        }
    }

    // epilogue: divide by l, store bf16 at [n*CHUNK + q][h*64 + d]
    #pragma unroll
    for (int dt = 0; dt < 4; ++dt)
        #pragma unroll
        for (int r = 0; r < 4; ++r) {
            float val = o_acc[dt][r] / l_run[r];
            size_t row = (size_t)n * CHUNK + qbase + quad * 4 + r;
            O[row * D_MODEL + h * HDIM + dt * 16 + cl] = f2bf(val);
        }
}

extern "C" void kernel_launch(void* const* d_in, const int* in_sizes, int n_in,
                              void* d_out, int out_size, void* d_ws, size_t ws_size,
                              hipStream_t stream) {
    const float* hs = (const float*)d_in[0];
    const float* Wq = (const float*)d_in[1];
    const float* Wk = (const float*)d_in[2];
    const float* Wv = (const float*)d_in[3];
    const float* Wo = (const float*)d_in[4];
    float* out = (float*)d_out;

    char* ws = (char*)d_ws;
    const size_t SZ_X = (size_t)SEQ * D_MODEL * sizeof(short);      // 16 MB
    const size_t SZ_W = (size_t)D_MODEL * D_MODEL * sizeof(short);  // 2 MB
    short* Xbf = (short*)(ws);
    short* Qbf = (short*)(ws + SZ_X);
    short* Kbf = (short*)(ws + 2 * SZ_X);
    short* Vbf = (short*)(ws + 3 * SZ_X);
    short* Abf = (short*)(ws + 4 * SZ_X);
    short* Wqb = (short*)(ws + 5 * SZ_X);
    short* Wkb = (short*)(ws + 5 * SZ_X + SZ_W);
    short* Wvb = (short*)(ws + 5 * SZ_X + 2 * SZ_W);
    short* Wob = (short*)(ws + 5 * SZ_X + 3 * SZ_W);

    const int nHS = SEQ * D_MODEL;        // 8388608
    const int nW  = D_MODEL * D_MODEL;    // 1048576
    cvt_f32_bf16<<<nHS / 1024, 256, 0, stream>>>(hs, Xbf, nHS);
    cvt_f32_bf16<<<nW / 1024, 256, 0, stream>>>(Wq, Wqb, nW);
    cvt_f32_bf16<<<nW / 1024, 256, 0, stream>>>(Wk, Wkb, nW);
    cvt_f32_bf16<<<nW / 1024, 256, 0, stream>>>(Wv, Wvb, nW);
    cvt_f32_bf16<<<nW / 1024, 256, 0, stream>>>(Wo, Wob, nW);

    dim3 gg(D_MODEL / 128, SEQ / 128);  // (8, 64)
    gemm_bt<true><<<gg, 256, 0, stream>>>(Xbf, Wqb, Qbf, SEQ, D_MODEL, D_MODEL);
    gemm_bt<true><<<gg, 256, 0, stream>>>(Xbf, Wkb, Kbf, SEQ, D_MODEL, D_MODEL);
    gemm_bt<true><<<gg, 256, 0, stream>>>(Xbf, Wvb, Vbf, SEQ, D_MODEL, D_MODEL);

    attn_kernel<<<dim3(CHUNK / 64, NCHUNK, NHEADS), 256, 0, stream>>>(Qbf, Kbf, Vbf, Abf);

    gemm_bt<false><<<gg, 256, 0, stream>>>(Abf, Wob, out, SEQ, D_MODEL, D_MODEL);
}

// Round 2
// 483.219 us; speedup vs baseline: 2.0302x; 2.0302x over previous
//
#include <hip/hip_runtime.h>
#include <stdint.h>

#define D_MODEL 1024
#define NHEADS 16
#define HDIM 64
#define CHUNK 2048
#define SEQ 8192
#define NCHUNK 4

typedef __attribute__((ext_vector_type(8))) short bf16x8;
typedef __attribute__((ext_vector_type(4))) float f32x4;

union V16 { uint4 u; short s[8]; };

static __device__ __forceinline__ short f2bf(float f) {
    unsigned int u = __builtin_bit_cast(unsigned int, f);
    u = (u + 0x7FFFu + ((u >> 16) & 1u)) >> 16;
    return (short)u;
}

static __device__ __forceinline__ void gl_lds16(const void* g, void* l) {
    __builtin_amdgcn_global_load_lds((__attribute__((address_space(1))) void*)g,
                                     (__attribute__((address_space(3))) void*)l,
                                     16, 0, 0);
}

// ---------------- fp32 -> bf16 conversion ----------------
__global__ void cvt_f32_bf16(const float* __restrict__ in, short* __restrict__ out, int n) {
    int i = (blockIdx.x * 256 + threadIdx.x) * 4;
    if (i >= n) return;
    float4 v = *(const float4*)(in + i);
    short4 o;
    o.x = f2bf(v.x); o.y = f2bf(v.y); o.z = f2bf(v.z); o.w = f2bf(v.w);
    *(short4*)(out + i) = o;
}

// ---------------- bf16 GEMM: C[M,N] = A[M,K] * B[N,K]^T ----------------
template<bool OUT_BF16>
__global__ __launch_bounds__(256) void gemm_bt(const short* __restrict__ A,
                                               const short* __restrict__ B,
                                               void* __restrict__ Cout,
                                               int M, int N, int K) {
    __shared__ __align__(16) short As[128 * 32];
    __shared__ __align__(16) short Bs[128 * 32];
    const int tid  = threadIdx.x;
    const int lane = tid & 63;
    const int w    = tid >> 6;
    const int wr   = w >> 1, wc = w & 1;
    const int rowBase = blockIdx.y * 128;
    const int colBase = blockIdx.x * 128;
    const int quad = lane >> 4;
    const int cl   = lane & 15;

    f32x4 acc[4][4];
    #pragma unroll
    for (int i = 0; i < 4; ++i)
        #pragma unroll
        for (int j = 0; j < 4; ++j)
            acc[i][j] = (f32x4){0.f, 0.f, 0.f, 0.f};

    const int tr = tid >> 2;
    const int tc = (tid & 3) * 8;
    const short* gA0 = A + (size_t)(rowBase + tr) * K + tc;
    const short* gA1 = A + (size_t)(rowBase + 64 + tr) * K + tc;
    const short* gB0 = B + (size_t)(colBase + tr) * K + tc;
    const short* gB1 = B + (size_t)(colBase + 64 + tr) * K + tc;

    for (int k0 = 0; k0 < K; k0 += 32) {
        gl_lds16(gA0 + k0, &As[tid * 8]);
        gl_lds16(gA1 + k0, &As[2048 + tid * 8]);
        gl_lds16(gB0 + k0, &Bs[tid * 8]);
        gl_lds16(gB1 + k0, &Bs[2048 + tid * 8]);
        __syncthreads();

        bf16x8 af[4], bfr[4];
        #pragma unroll
        for (int mi = 0; mi < 4; ++mi)
            af[mi] = *(const bf16x8*)&As[(wr * 64 + mi * 16 + cl) * 32 + quad * 8];
        #pragma unroll
        for (int ni = 0; ni < 4; ++ni)
            bfr[ni] = *(const bf16x8*)&Bs[(wc * 64 + ni * 16 + cl) * 32 + quad * 8];

        #pragma unroll
        for (int mi = 0; mi < 4; ++mi)
            #pragma unroll
            for (int ni = 0; ni < 4; ++ni)
                acc[mi][ni] = __builtin_amdgcn_mfma_f32_16x16x32_bf16(af[mi], bfr[ni], acc[mi][ni], 0, 0, 0);
        __syncthreads();
    }

    #pragma unroll
    for (int mi = 0; mi < 4; ++mi)
        #pragma unroll
        for (int ni = 0; ni < 4; ++ni)
            #pragma unroll
            for (int r = 0; r < 4; ++r) {
                int row = rowBase + wr * 64 + mi * 16 + quad * 4 + r;
                int col = colBase + wc * 64 + ni * 16 + cl;
                if (OUT_BF16)
                    ((short*)Cout)[(size_t)row * N + col] = f2bf(acc[mi][ni][r]);
                else
                    ((float*)Cout)[(size_t)row * N + col] = acc[mi][ni][r];
            }
}

// ---------------- V transpose: V[seq][1024] -> VT[h][n][d][key] ----------------
// VT index = ((h*NCHUNK + n)*HDIM + d)*CHUNK + key
__global__ __launch_bounds__(256) void transpose_v(const short* __restrict__ V,
                                                   short* __restrict__ VT) {
    __shared__ __align__(16) short Lt[64 * 64];
    const int tid = threadIdx.x;
    const int r0 = blockIdx.x * 64;   // seq base (within one chunk: 64 | 2048)
    const int c0 = blockIdx.y * 64;   // col base = h*64
    const int n = r0 >> 11;
    const int key0 = r0 & 2047;
    const int h = c0 >> 6;

    #pragma unroll
    for (int i = 0; i < 2; ++i) {
        int rr = i * 32 + (tid >> 3);
        int c8 = tid & 7;
        V16 v;
        v.u = *(const uint4*)(V + (size_t)(r0 + rr) * D_MODEL + c0 + c8 * 8);
        #pragma unroll
        for (int j = 0; j < 8; ++j) {
            int c = c8 * 8 + j;
            int slot = c * 8 + ((rr >> 3) ^ ((c >> 3) & 7));
            Lt[slot * 8 + (rr & 7)] = v.s[j];
        }
    }
    __syncthreads();
    #pragma unroll
    for (int i = 0; i < 2; ++i) {
        int dd = i * 32 + (tid >> 3);
        int k8 = tid & 7;
        int slot = dd * 8 + (k8 ^ ((dd >> 3) & 7));
        uint4 o = *(const uint4*)(Lt + slot * 8);
        *(uint4*)(VT + ((size_t)(h * NCHUNK + n) * HDIM + dd) * CHUNK + key0 + k8 * 8) = o;
    }
}

// ---------------- flash attention, chunk-local causal ----------------
// grid: (CHUNK/128, NCHUNK, NHEADS), block 256 = 4 waves; wave w owns q rows
// [qb0+32w, qb0+32w+32) as two 16-row MFMA strips. Shared 64-key K/V tiles.
__global__ __launch_bounds__(256, 2) void attn_kernel(const short* __restrict__ Q,
                                                      const short* __restrict__ K,
                                                      const short* __restrict__ VT,
                                                      short* __restrict__ O) {
    __shared__ __align__(16) short Kt[64 * 64];   // swizzled [key][d]
    __shared__ __align__(16) short Vt[64 * 64];   // swizzled [d][key]
    __shared__ __align__(16) short Pt[4 * 32 * 64]; // per-wave swizzled [m][key]
    const int tid  = threadIdx.x;
    const int lane = tid & 63;
    const int w    = tid >> 6;
    const int quad = lane >> 4;
    const int cl   = lane & 15;
    const int h = blockIdx.z;
    const int n = blockIdx.y;
    const int qb0 = blockIdx.x * 128;
    const int s0  = qb0 + w * 32;  // strip 0 base (chunk-local); strip 1 = s0+16

    const short* Qg  = Q + (size_t)n * CHUNK * D_MODEL + h * HDIM;
    const short* Kg  = K + (size_t)n * CHUNK * D_MODEL + h * HDIM;
    const short* VTg = VT + (size_t)(h * NCHUNK + n) * HDIM * CHUNK;
    short* Pw = Pt + w * 2048;

    // Q fragments: A[m=cl][k=half*32+quad*8+j]
    bf16x8 qf[2][2];
    #pragma unroll
    for (int st = 0; st < 2; ++st)
        #pragma unroll
        for (int hf = 0; hf < 2; ++hf)
            qf[st][hf] = *(const bf16x8*)(Qg + (size_t)(s0 + st * 16 + cl) * D_MODEL + hf * 32 + quad * 8);

    float m_run[2][4], l_run[2][4];
    f32x4 o_acc[2][4];
    #pragma unroll
    for (int st = 0; st < 2; ++st) {
        #pragma unroll
        for (int r = 0; r < 4; ++r) { m_run[st][r] = -3.0e38f; l_run[st][r] = 0.f; }
        #pragma unroll
        for (int dt = 0; dt < 4; ++dt) o_acc[st][dt] = (f32x4){0.f, 0.f, 0.f, 0.f};
    }

    const float cs = 0.18033688011f;  // log2(e)/sqrt(64)
    const int ntiles = qb0 / 64 + 2;

    for (int t = 0; t < ntiles; ++t) {
        const int kb = t * 64;
        __syncthreads();  // prior-iter LDS reads complete before restage
        #pragma unroll
        for (int j = 0; j < 2; ++j) {
            int s = j * 256 + tid;
            int row = s >> 3;
            int b = (s & 7) ^ (row & 7);
            gl_lds16(Kg + (size_t)(kb + row) * D_MODEL + b * 8, Kt + s * 8);
            gl_lds16(VTg + (size_t)row * CHUNK + kb + b * 8, Vt + s * 8);
        }
        __syncthreads();  // drains vmcnt: staged data visible

        // ---- S = Q K^T for both strips ----
        bf16x8 kf[4][2];
        #pragma unroll
        for (int kt = 0; kt < 4; ++kt)
            #pragma unroll
            for (int hf = 0; hf < 2; ++hf) {
                int key = kt * 16 + cl;
                int slot = key * 8 + ((hf * 4 + quad) ^ (key & 7));
                kf[kt][hf] = *(const bf16x8*)(Kt + slot * 8);
            }

        #pragma unroll
        for (int st = 0; st < 2; ++st) {
            const int sb = s0 + st * 16;
            if (kb > sb + 15) continue;  // strip fully masked (wave-uniform)
            f32x4 sa[4];
            #pragma unroll
            for (int kt = 0; kt < 4; ++kt) {
                sa[kt] = (f32x4){0.f, 0.f, 0.f, 0.f};
                sa[kt] = __builtin_amdgcn_mfma_f32_16x16x32_bf16(qf[st][0], kf[kt][0], sa[kt], 0, 0, 0);
                sa[kt] = __builtin_amdgcn_mfma_f32_16x16x32_bf16(qf[st][1], kf[kt][1], sa[kt], 0, 0, 0);
            }
            const bool full = (kb + 63) <= sb;
            #pragma unroll
            for (int r = 0; r < 4; ++r) {
                float v0 = sa[0][r], v1 = sa[1][r], v2 = sa[2][r], v3 = sa[3][r];
                if (!full) {
                    int q = sb + quad * 4 + r;
                    if (kb + cl > q)      v0 = -3.0e38f;
                    if (kb + 16 + cl > q) v1 = -3.0e38f;
                    if (kb + 32 + cl > q) v2 = -3.0e38f;
                    if (kb + 48 + cl > q) v3 = -3.0e38f;
                }
                float mx = fmaxf(fmaxf(v0, v1), fmaxf(v2, v3));
                mx = fmaxf(mx, __shfl_xor(mx, 1));
                mx = fmaxf(mx, __shfl_xor(mx, 2));
                mx = fmaxf(mx, __shfl_xor(mx, 4));
                mx = fmaxf(mx, __shfl_xor(mx, 8));
                float mnew = fmaxf(m_run[st][r], mx);
                float alpha = __builtin_amdgcn_exp2f((m_run[st][r] - mnew) * cs);
                float nm = mnew * cs;
                float p0 = __builtin_amdgcn_exp2f(__builtin_fmaf(v0, cs, -nm));
                float p1 = __builtin_amdgcn_exp2f(__builtin_fmaf(v1, cs, -nm));
                float p2 = __builtin_amdgcn_exp2f(__builtin_fmaf(v2, cs, -nm));
                float p3 = __builtin_amdgcn_exp2f(__builtin_fmaf(v3, cs, -nm));
                float rs = (p0 + p1) + (p2 + p3);
                rs += __shfl_xor(rs, 1);
                rs += __shfl_xor(rs, 2);
                rs += __shfl_xor(rs, 4);
                rs += __shfl_xor(rs, 8);
                l_run[st][r] = l_run[st][r] * alpha + rs;
                m_run[st][r] = mnew;
                #pragma unroll
                for (int dt = 0; dt < 4; ++dt) o_acc[st][dt][r] *= alpha;
                // P write, swizzled: slot = mm*8 + (colblk ^ (mm&7))
                int mm = st * 16 + quad * 4 + r;
                int sw = mm & 7;
                Pw[(mm * 8 + ((0 + (cl >> 3)) ^ sw)) * 8 + (cl & 7)] = f2bf(p0);
                Pw[(mm * 8 + ((2 + (cl >> 3)) ^ sw)) * 8 + (cl & 7)] = f2bf(p1);
                Pw[(mm * 8 + ((4 + (cl >> 3)) ^ sw)) * 8 + (cl & 7)] = f2bf(p2);
                Pw[(mm * 8 + ((6 + (cl >> 3)) ^ sw)) * 8 + (cl & 7)] = f2bf(p3);
            }
        }
        __asm__ volatile("s_waitcnt lgkmcnt(0)" ::: "memory");

        // ---- O += P V ----
        bf16x8 vf[4][2];
        #pragma unroll
        for (int dt = 0; dt < 4; ++dt)
            #pragma unroll
            for (int kc = 0; kc < 2; ++kc) {
                int d = dt * 16 + cl;
                int slot = d * 8 + ((kc * 4 + quad) ^ (d & 7));
                vf[dt][kc] = *(const bf16x8*)(Vt + slot * 8);
            }
        #pragma unroll
        for (int st = 0; st < 2; ++st) {
            const int sb = s0 + st * 16;
            if (kb > sb + 15) continue;
            bf16x8 pf[2];
            #pragma unroll
            for (int kc = 0; kc < 2; ++kc) {
                int m = st * 16 + cl;
                int slot = m * 8 + ((kc * 4 + quad) ^ (m & 7));
                pf[kc] = *(const bf16x8*)(Pw + slot * 8);
            }
            #pragma unroll
            for (int dt = 0; dt < 4; ++dt) {
                o_acc[st][dt] = __builtin_amdgcn_mfma_f32_16x16x32_bf16(pf[0], vf[dt][0], o_acc[st][dt], 0, 0, 0);
                o_acc[st][dt] = __builtin_amdgcn_mfma_f32_16x16x32_bf16(pf[1], vf[dt][1], o_acc[st][dt], 0, 0, 0);
            }
        }
    }

    // epilogue
    #pragma unroll
    for (int st = 0; st < 2; ++st)
        #pragma unroll
        for (int dt = 0; dt < 4; ++dt)
            #pragma unroll
            for (int r = 0; r < 4; ++r) {
                float val = o_acc[st][dt][r] / l_run[st][r];
                size_t row = (size_t)n * CHUNK + s0 + st * 16 + quad * 4 + r;
                O[row * D_MODEL + h * HDIM + dt * 16 + cl] = f2bf(val);
            }
}

extern "C" void kernel_launch(void* const* d_in, const int* in_sizes, int n_in,
                              void* d_out, int out_size, void* d_ws, size_t ws_size,
                              hipStream_t stream) {
    const float* hs = (const float*)d_in[0];
    const float* Wq = (const float*)d_in[1];
    const float* Wk = (const float*)d_in[2];
    const float* Wv = (const float*)d_in[3];
    const float* Wo = (const float*)d_in[4];
    float* out = (float*)d_out;

    char* ws = (char*)d_ws;
    const size_t SZ_X = (size_t)SEQ * D_MODEL * sizeof(short);      // 16 MB
    const size_t SZ_W = (size_t)D_MODEL * D_MODEL * sizeof(short);  // 2 MB
    short* Xbf = (short*)(ws);                    // also reused as VT after GEMMs
    short* Qbf = (short*)(ws + SZ_X);
    short* Kbf = (short*)(ws + 2 * SZ_X);
    short* Vbf = (short*)(ws + 3 * SZ_X);
    short* Abf = (short*)(ws + 4 * SZ_X);
    short* Wqb = (short*)(ws + 5 * SZ_X);
    short* Wkb = (short*)(ws + 5 * SZ_X + SZ_W);
    short* Wvb = (short*)(ws + 5 * SZ_X + 2 * SZ_W);
    short* Wob = (short*)(ws + 5 * SZ_X + 3 * SZ_W);
    short* VT  = Xbf;  // X dead after the three QKV GEMMs

    const int nHS = SEQ * D_MODEL;
    const int nW  = D_MODEL * D_MODEL;
    cvt_f32_bf16<<<nHS / 1024, 256, 0, stream>>>(hs, Xbf, nHS);
    cvt_f32_bf16<<<nW / 1024, 256, 0, stream>>>(Wq, Wqb, nW);
    cvt_f32_bf16<<<nW / 1024, 256, 0, stream>>>(Wk, Wkb, nW);
    cvt_f32_bf16<<<nW / 1024, 256, 0, stream>>>(Wv, Wvb, nW);
    cvt_f32_bf16<<<nW / 1024, 256, 0, stream>>>(Wo, Wob, nW);

    dim3 gg(D_MODEL / 128, SEQ / 128);
    gemm_bt<true><<<gg, 256, 0, stream>>>(Xbf, Wqb, Qbf, SEQ, D_MODEL, D_MODEL);
    gemm_bt<true><<<gg, 256, 0, stream>>>(Xbf, Wkb, Kbf, SEQ, D_MODEL, D_MODEL);
    gemm_bt<true><<<gg, 256, 0, stream>>>(Xbf, Wvb, Vbf, SEQ, D_MODEL, D_MODEL);

    transpose_v<<<dim3(SEQ / 64, D_MODEL / 64), 256, 0, stream>>>(Vbf, VT);

    attn_kernel<<<dim3(CHUNK / 128, NCHUNK, NHEADS), 256, 0, stream>>>(Qbf, Kbf, VT, Abf);

    gemm_bt<false><<<gg, 256, 0, stream>>>(Abf, Wob, out, SEQ, D_MODEL, D_MODEL);
}